// Round 12
// baseline (485.814 us; speedup 1.0000x reference)
//
#include <hip/hip_runtime.h>
#include <hip/hip_bf16.h>
#include <cstdint>
#include <cstddef>

#define NAT 16384
#define NED 65536
#define BGR 256
#define FIN 64
#define HID 256
#define LPN 1024
#define HD 64
#define NTRIP 11638          // 23*22*23 distinct (t0,t1,t2) conv triples
#define NTAB  11648          // padded to multiple of 128 for MFMA tiles

typedef __bf16 bf16x8 __attribute__((ext_vector_type(8)));
typedef float floatx4 __attribute__((ext_vector_type(4)));

// async global->LDS 16B; dest = wave-uniform base + lane*16 (linear layout!)
__device__ __forceinline__ void gl2lds16(const void* g, void* l)
{
    __builtin_amdgcn_global_load_lds(
        (const __attribute__((address_space(1))) unsigned int*)g,
        (__attribute__((address_space(3))) unsigned int*)l, 16, 0, 0);
}

// ---------------- bf16 MFMA GEMM, 8-wave, BK=64 double sub-buffer ------------
template<int ACT, int OUTBF16, int BIASROW, int HSPLIT, int NCOL>
__global__ __launch_bounds__(512) void gemm_mfma(const __bf16* __restrict__ A,
    const __bf16* __restrict__ Bt, const float* __restrict__ bias,
    void* __restrict__ Cout, int M, int Nn, int K, float escale)
{
    constexpr int NJ = NCOL / 32;
    __shared__ __bf16 As[2][128][32];
    __shared__ __bf16 Bs[2][NCOL][32];
    const int t = threadIdx.x;
    const int m0 = blockIdx.y * 128, n0 = blockIdx.x * NCOL;
    const int w = t >> 6, lane = t & 63;
    const int wm = (w & 3) * 32, wn = (w >> 2) * (NCOL / 2);
    const int quad = lane >> 4, l16 = lane & 15;
    const int r0 = t >> 2, s0 = t & 3, g0 = (s0 ^ (r0 & 3)) * 8;
    const int fso = (quad ^ (l16 & 3)) * 8;
    floatx4 acc[2][NJ] = {};
    for (int k0 = 0; k0 < K; k0 += 64) {
        gl2lds16(A + (size_t)(m0 + r0) * K + k0 + g0,       &As[0][r0][s0 * 8]);
        gl2lds16(A + (size_t)(m0 + r0) * K + k0 + 32 + g0,  &As[1][r0][s0 * 8]);
        if (NCOL == 128 || t < 256) {
            gl2lds16(Bt + (size_t)(n0 + r0) * K + k0 + g0,      &Bs[0][r0][s0 * 8]);
            gl2lds16(Bt + (size_t)(n0 + r0) * K + k0 + 32 + g0, &Bs[1][r0][s0 * 8]);
        }
        __syncthreads();
#pragma unroll
        for (int c = 0; c < 2; c++) {
            bf16x8 af[2], bfr[NJ];
#pragma unroll
            for (int mi = 0; mi < 2; mi++) af[mi]  = *(const bf16x8*)&As[c][wm + mi * 16 + l16][fso];
#pragma unroll
            for (int nj = 0; nj < NJ; nj++) bfr[nj] = *(const bf16x8*)&Bs[c][wn + nj * 16 + l16][fso];
#pragma unroll
            for (int mi = 0; mi < 2; mi++)
#pragma unroll
                for (int nj = 0; nj < NJ; nj++)
                    acc[mi][nj] = __builtin_amdgcn_mfma_f32_16x16x32_bf16(af[mi], bfr[nj], acc[mi][nj], 0, 0, 0);
        }
        __syncthreads();
    }
#pragma unroll
    for (int mi = 0; mi < 2; mi++)
#pragma unroll
        for (int nj = 0; nj < NJ; nj++) {
            int col = n0 + wn + nj * 16 + l16;
#pragma unroll
            for (int r = 0; r < 4; r++) {
                int row = m0 + wm + mi * 16 + quad * 4 + r;
                float bval = bias ? (BIASROW ? bias[row] : bias[col]) : 0.f;
                float v = (acc[mi][nj][r] + bval) * escale;
                if (ACT == 1) v = fmaxf(v, 0.f);
                if (ACT == 2) v = 0.5f * v * (1.f + erff(v * 0.70710678118654752f));
                if (HSPLIT)      ((__bf16*)Cout)[((size_t)(col >> 6) * M + row) * 64 + (col & 63)] = (__bf16)v;
                else if (OUTBF16) ((__bf16*)Cout)[(size_t)row * Nn + col] = (__bf16)v;
                else              ((float*)Cout)[(size_t)row * Nn + col] = v;
            }
        }
}

// ---------------- GAT feature GEMM (no epilogue partials now) ----------------
__global__ __launch_bounds__(512) void gemm_gat(const __bf16* __restrict__ A,
    const __bf16* __restrict__ Bt, __bf16* __restrict__ Hg, int K)
{
    __shared__ __bf16 As[2][128][32];
    __shared__ __bf16 Bs[2][128][32];
    const int t = threadIdx.x;
    const int m0 = blockIdx.y * 128, n0 = blockIdx.x * 128;
    const int w = t >> 6, lane = t & 63;
    const int wm = (w & 3) * 32, wn = (w >> 2) * 64;
    const int quad = lane >> 4, l16 = lane & 15;
    const int r0 = t >> 2, s0 = t & 3, g0 = (s0 ^ (r0 & 3)) * 8;
    const int fso = (quad ^ (l16 & 3)) * 8;
    floatx4 acc[2][4] = {};
    for (int k0 = 0; k0 < K; k0 += 64) {
        gl2lds16(A + (size_t)(m0 + r0) * K + k0 + g0,       &As[0][r0][s0 * 8]);
        gl2lds16(A + (size_t)(m0 + r0) * K + k0 + 32 + g0,  &As[1][r0][s0 * 8]);
        gl2lds16(Bt + (size_t)(n0 + r0) * K + k0 + g0,      &Bs[0][r0][s0 * 8]);
        gl2lds16(Bt + (size_t)(n0 + r0) * K + k0 + 32 + g0, &Bs[1][r0][s0 * 8]);
        __syncthreads();
#pragma unroll
        for (int c = 0; c < 2; c++) {
            bf16x8 af[2], bfr[4];
#pragma unroll
            for (int mi = 0; mi < 2; mi++) af[mi]  = *(const bf16x8*)&As[c][wm + mi * 16 + l16][fso];
#pragma unroll
            for (int nj = 0; nj < 4; nj++) bfr[nj] = *(const bf16x8*)&Bs[c][wn + nj * 16 + l16][fso];
#pragma unroll
            for (int mi = 0; mi < 2; mi++)
#pragma unroll
                for (int nj = 0; nj < 4; nj++)
                    acc[mi][nj] = __builtin_amdgcn_mfma_f32_16x16x32_bf16(af[mi], bfr[nj], acc[mi][nj], 0, 0, 0);
        }
        __syncthreads();
    }
#pragma unroll
    for (int mi = 0; mi < 2; mi++)
#pragma unroll
        for (int nj = 0; nj < 4; nj++) {
            int col = n0 + wn + nj * 16 + l16;
#pragma unroll
            for (int r = 0; r < 4; r++) {
                int row = m0 + wm + mi * 16 + quad * 4 + r;
                Hg[(size_t)row * 512 + col] = (__bf16)acc[mi][nj][r];
            }
        }
}

// ---------------- single fused conversion kernel ----------------
struct Segs {
    const float* src[12];
    __bf16* dst[12];
    int kdim[12];
    int ndim[12];
    int mode[12];          // 0 copy, 1 transpose
    int start[13];
};

// ---------------- fused preamble 1: deg + tap + tid + wasd + cvtall ----------
// wasd[l][k][4] = {W_l[:,g0]@as_g0, W_l[:,g1]@as_g1, same for ad} per input k
__global__ __launch_bounds__(256) void misc1_k(const int* __restrict__ ei,
    int* __restrict__ deg, const float* __restrict__ emb,
    const float* __restrict__ cw, float* __restrict__ tap,
    const int* __restrict__ seq, unsigned short* __restrict__ tid,
    const float* __restrict__ wl0, const float* __restrict__ wl1,
    const float* __restrict__ wl2,
    const float* __restrict__ as1, const float* __restrict__ as2,
    const float* __restrict__ as3,
    const float* __restrict__ ad1, const float* __restrict__ ad2,
    const float* __restrict__ ad3, float* __restrict__ wasd,
    Segs S, int total)
{
    const int bid = blockIdx.x;
    const int t = threadIdx.x;
    if (bid < 256) {
        int e = bid * 256 + t;
        atomicAdd(&deg[ei[NED + e]], 1);
    } else if (bid < 322) {
        // deterministic conv tap: tap[dlv][n] = sum_ic emb[v][ic]*cw[n][ic][dl]
        const int dlv = bid - 256;
        const int dl = dlv / 22, v = dlv % 22;
        const float* er = emb + v * 256;
        const float* wr = cw + (size_t)t * 768 + dl;
        float s = 0.f;
        for (int k = 0; k < 256; k += 4) {
            s += er[k + 0] * wr[(k + 0) * 3];
            s += er[k + 1] * wr[(k + 1) * 3];
            s += er[k + 2] * wr[(k + 2) * 3];
            s += er[k + 3] * wr[(k + 3) * 3];
        }
        tap[(size_t)dlv * 256 + t] = s;
    } else if (bid < 1346) {
        int i = (bid - 322) * 256 + t;
        int b = i >> 10, l = i & 1023;
        const int* sr = seq + b * LPN;
        int t0 = (l > 0) ? sr[l - 1] : -1;
        int t1 = sr[l];
        int t2 = (l < LPN - 1) ? sr[l + 1] : -1;
        int v = (t0 + 1) * 506 + t1 * 23 + (t2 + 1);
        tid[i] = (unsigned short)(v | (t1 == 0 ? 0x8000 : 0));
    } else if (bid < 1349) {
        const int l = bid - 1346;
        const int Kl = l ? 256 : 64;
        if (t < Kl) {
            const float* Wr = (l == 0 ? wl0 : (l == 1 ? wl1 : wl2)) + (size_t)t * 512;
            const float* asl = (l == 0 ? as1 : (l == 1 ? as2 : as3));
            const float* adl = (l == 0 ? ad1 : (l == 1 ? ad2 : ad3));
            float s0 = 0.f, s1 = 0.f, d0 = 0.f, d1 = 0.f;
            for (int c = 0; c < 256; c++) {
                float w0 = Wr[c], w1v = Wr[256 + c];
                s0 += w0 * asl[c];       s1 += w1v * asl[256 + c];
                d0 += w0 * adl[c];       d1 += w1v * adl[256 + c];
            }
            float* o = wasd + (size_t)(l * 256 + t) * 4;
            o[0] = s0; o[1] = s1; o[2] = d0; o[3] = d1;
        }
    } else {
        int i = (bid - 1349) * 256 + t;
        if (i >= total) return;
        int s = 0;
        while (i >= S.start[s + 1]) s++;
        int j = i - S.start[s];
        if (S.mode[s] == 0) {
            S.dst[s][j] = (__bf16)S.src[s][j];
        } else {
            int K = S.kdim[s], N = S.ndim[s];
            int n = j / K, k = j - n * K;
            S.dst[s][j] = (__bf16)S.src[s][(size_t)k * N + n];
        }
    }
}

// ---------------- fused preamble 2: scan (block 0) + ptab --------------------
__global__ __launch_bounds__(256) void misc2_k(const int* __restrict__ deg,
    int* __restrict__ rowptr, const float* __restrict__ tap,
    const float* __restrict__ bias, __bf16* __restrict__ P)
{
    __shared__ int part[256];
    const int t = threadIdx.x;
    if (blockIdx.x == 0) {
        int base = t * 64;
        int s = 0;
#pragma unroll
        for (int i = 0; i < 64; i++) s += deg[base + i];
        part[t] = s;
        __syncthreads();
        for (int off = 1; off < 256; off <<= 1) {
            int v = (t >= off) ? part[t - off] : 0;
            __syncthreads();
            part[t] += v;
            __syncthreads();
        }
        int run = t ? part[t - 1] : 0;
        for (int i = 0; i < 64; i++) { rowptr[base + i] = run; run += deg[base + i]; }
        if (t == 255) rowptr[16384] = run;
    } else {
        const int row = (blockIdx.x - 1) * 8 + (t >> 5);
        const int c = (t & 31) * 8;
        __bf16 o[8];
        if (row < NTRIP) {
            const int a = row / 506, rem = row - a * 506;
            const int t1 = rem / 23, c2 = rem - t1 * 23;
            float acc[8];
#pragma unroll
            for (int j = 0; j < 8; j++) acc[j] = bias[c + j];
            if (a > 0) {
                const float* r = tap + (size_t)(0 * 22 + (a - 1)) * 256 + c;
#pragma unroll
                for (int j = 0; j < 8; j++) acc[j] += r[j];
            }
            {
                const float* r = tap + (size_t)(1 * 22 + t1) * 256 + c;
#pragma unroll
                for (int j = 0; j < 8; j++) acc[j] += r[j];
            }
            if (c2 > 0) {
                const float* r = tap + (size_t)(2 * 22 + (c2 - 1)) * 256 + c;
#pragma unroll
                for (int j = 0; j < 8; j++) acc[j] += r[j];
            }
#pragma unroll
            for (int j = 0; j < 8; j++) o[j] = (__bf16)fmaxf(acc[j], 0.f);
        } else {
#pragma unroll
            for (int j = 0; j < 8; j++) o[j] = (__bf16)0.f;
        }
        *(uint4*)(P + (size_t)row * 256 + c) = *(uint4*)o;
    }
}

// ---------------- fused preamble 3: scat + kvtab + layer0 a_s/a_d ------------
__global__ __launch_bounds__(512) void misc3_k(const int* __restrict__ ei,
    int* __restrict__ fill, const int* __restrict__ rowptr,
    int* __restrict__ csrc, int* __restrict__ cdst,
    const __bf16* __restrict__ A, const __bf16* __restrict__ wkT,
    const __bf16* __restrict__ wvT, const float* __restrict__ bk,
    const float* __restrict__ bv, __bf16* __restrict__ Ktab,
    __bf16* __restrict__ Vtab,
    const __bf16* __restrict__ xb, const float* __restrict__ wasd0,
    float* __restrict__ as0, float* __restrict__ ad0)
{
    __shared__ __bf16 As[2][128][32];
    __shared__ __bf16 Bs[2][128][32];
    const int t = threadIdx.x;
    if (blockIdx.x < 128) {
        int e = blockIdx.x * 512 + t;
        if (e >= NED) return;
        int d = ei[NED + e];
        int pos = rowptr[d] + atomicAdd(&fill[d], 1);
        csrc[pos] = ei[e];
        cdst[pos] = d;
        return;
    }
    if (blockIdx.x >= 492) {
        // layer-0 logit vectors: a_s0[n][g] = xb[n,:] @ wasd0[:,g]
        const int node = (blockIdx.x - 492) * 64 + (t >> 3);
        const int l8 = t & 7;
        bf16x8 xv = *(const bf16x8*)(xb + (size_t)node * 64 + l8 * 8);
        float p0 = 0.f, p1 = 0.f, p2 = 0.f, p3 = 0.f;
#pragma unroll
        for (int j = 0; j < 8; j++) {
            float xf = (float)xv[j];
            float4 w4 = *(const float4*)(wasd0 + (size_t)(l8 * 8 + j) * 4);
            p0 += xf * w4.x; p1 += xf * w4.y; p2 += xf * w4.z; p3 += xf * w4.w;
        }
#pragma unroll
        for (int off = 1; off < 8; off <<= 1) {
            p0 += __shfl_xor(p0, off, 64);
            p1 += __shfl_xor(p1, off, 64);
            p2 += __shfl_xor(p2, off, 64);
            p3 += __shfl_xor(p3, off, 64);
        }
        if (l8 == 0) {
            as0[node * 2 + 0] = p0; as0[node * 2 + 1] = p1;
            ad0[node * 2 + 0] = p2; ad0[node * 2 + 1] = p3;
        }
        return;
    }
    const int lb = blockIdx.x - 128;
    const int bx = lb & 3, by = lb >> 2;
    const int z = bx >> 1;
    const int m0 = by * 128, n0 = (bx & 1) * 128;
    const __bf16* Bt = z ? wvT : wkT;
    const float* bias = z ? bv : bk;
    __bf16* Cout = z ? Vtab : Ktab;
    const int w = t >> 6, lane = t & 63;
    const int wm = (w & 3) * 32, wn = (w >> 2) * 64;
    const int quad = lane >> 4, l16 = lane & 15;
    const int r0 = t >> 2, s0 = t & 3, g0 = (s0 ^ (r0 & 3)) * 8;
    const int fso = (quad ^ (l16 & 3)) * 8;
    floatx4 acc[2][4] = {};
    for (int k0 = 0; k0 < 256; k0 += 64) {
        gl2lds16(A + (size_t)(m0 + r0) * 256 + k0 + g0,       &As[0][r0][s0 * 8]);
        gl2lds16(A + (size_t)(m0 + r0) * 256 + k0 + 32 + g0,  &As[1][r0][s0 * 8]);
        gl2lds16(Bt + (size_t)(n0 + r0) * 256 + k0 + g0,      &Bs[0][r0][s0 * 8]);
        gl2lds16(Bt + (size_t)(n0 + r0) * 256 + k0 + 32 + g0, &Bs[1][r0][s0 * 8]);
        __syncthreads();
#pragma unroll
        for (int c = 0; c < 2; c++) {
            bf16x8 af[2], bfr[4];
#pragma unroll
            for (int mi = 0; mi < 2; mi++) af[mi]  = *(const bf16x8*)&As[c][wm + mi * 16 + l16][fso];
#pragma unroll
            for (int nj = 0; nj < 4; nj++) bfr[nj] = *(const bf16x8*)&Bs[c][wn + nj * 16 + l16][fso];
#pragma unroll
            for (int mi = 0; mi < 2; mi++)
#pragma unroll
                for (int nj = 0; nj < 4; nj++)
                    acc[mi][nj] = __builtin_amdgcn_mfma_f32_16x16x32_bf16(af[mi], bfr[nj], acc[mi][nj], 0, 0, 0);
        }
        __syncthreads();
    }
#pragma unroll
    for (int mi = 0; mi < 2; mi++)
#pragma unroll
        for (int nj = 0; nj < 4; nj++) {
            int col = n0 + wn + nj * 16 + l16;
#pragma unroll
            for (int r = 0; r < 4; r++) {
                int row = m0 + wm + mi * 16 + quad * 4 + r;
                float v = acc[mi][nj][r] + bias[col];
                Cout[((size_t)(col >> 6) * NTAB + row) * 64 + (col & 63)] = (__bf16)v;
            }
        }
}

// ---------------- fused GAT aggregation (inline e; next-layer a_s/a_d) -------
__global__ __launch_bounds__(256) void gat_agg(const int* __restrict__ rowptr,
    const int* __restrict__ csrc, const __bf16* __restrict__ hgb,
    const float* __restrict__ a_s, const float* __restrict__ a_d,
    const float* __restrict__ bias, const float* __restrict__ wasd_next,
    float* __restrict__ as_out, float* __restrict__ ad_out,
    float* __restrict__ out, __bf16* __restrict__ outb)
{
    const int wave = threadIdx.x >> 6, lane = threadIdx.x & 63;
    const int d = blockIdx.x * 4 + wave;
    const int beg = rowptr[d], end = rowptr[d + 1];
    float2 as2 = *(const float2*)(a_s + d * 2);
    float2 ad2 = *(const float2*)(a_d + d * 2);
    float e0 = as2.x + ad2.x; e0 = (e0 > 0.f) ? e0 : 0.2f * e0;
    float e1 = as2.y + ad2.y; e1 = (e1 > 0.f) ? e1 : 0.2f * e1;
    float m0 = e0, den0 = 1.f, m1 = e1, den1 = 1.f;
    for (int p = beg; p < end; p++) {
        int s = csrc[p];
        float2 av = *(const float2*)(a_s + s * 2);
        float f0 = av.x + ad2.x; f0 = (f0 > 0.f) ? f0 : 0.2f * f0;
        float f1 = av.y + ad2.y; f1 = (f1 > 0.f) ? f1 : 0.2f * f1;
        float nm0 = fmaxf(m0, f0);
        den0 = den0 * __expf(m0 - nm0) + __expf(f0 - nm0);
        m0 = nm0;
        float nm1 = fmaxf(m1, f1);
        den1 = den1 * __expf(m1 - nm1) + __expf(f1 - nm1);
        m1 = nm1;
    }
    const float inv0 = 1.f / den0, inv1 = 1.f / den1;
    const int ch = lane * 8;
    const int g = ch >> 8;
    const float mg = g ? m1 : m0, invg = g ? inv1 : inv0;
    float acc[8] = {};
    {
        float al = __expf((g ? e1 : e0) - mg) * invg;
        bf16x8 hv = *(const bf16x8*)(hgb + (size_t)d * 512 + ch);
#pragma unroll
        for (int j = 0; j < 8; j++) acc[j] += (float)hv[j] * al;
    }
    for (int p = beg; p < end; p++) {
        int s = csrc[p];
        float2 av = *(const float2*)(a_s + s * 2);
        float f0 = av.x + ad2.x; f0 = (f0 > 0.f) ? f0 : 0.2f * f0;
        float f1 = av.y + ad2.y; f1 = (f1 > 0.f) ? f1 : 0.2f * f1;
        float al = __expf((g ? f1 : f0) - mg) * invg;
        bf16x8 hv = *(const bf16x8*)(hgb + (size_t)s * 512 + ch);
#pragma unroll
        for (int j = 0; j < 8; j++) acc[j] += (float)hv[j] * al;
    }
    float other[8];
#pragma unroll
    for (int j = 0; j < 8; j++) other[j] = __shfl_xor(acc[j], 32, 64);
    if (lane < 32) {
        float vv[8];
#pragma unroll
        for (int j = 0; j < 8; j++) {
            float v = 0.5f * (acc[j] + other[j]) + bias[ch + j];
            v = (v > 0.f) ? v : expm1f(v);
            vv[j] = v;
            if (out) out[(size_t)d * 256 + ch + j] = v;
            outb[(size_t)d * 256 + ch + j] = (__bf16)v;
        }
        if (wasd_next) {
            float p0 = 0.f, p1 = 0.f, p2 = 0.f, p3 = 0.f;
#pragma unroll
            for (int j = 0; j < 8; j++) {
                float4 w4 = *(const float4*)(wasd_next + (size_t)(ch + j) * 4);
                p0 += vv[j] * w4.x; p1 += vv[j] * w4.y;
                p2 += vv[j] * w4.z; p3 += vv[j] * w4.w;
            }
#pragma unroll
            for (int off = 1; off < 32; off <<= 1) {
                p0 += __shfl_xor(p0, off, 64);
                p1 += __shfl_xor(p1, off, 64);
                p2 += __shfl_xor(p2, off, 64);
                p3 += __shfl_xor(p3, off, 64);
            }
            if (lane == 0) {
                as_out[d * 2 + 0] = p0; as_out[d * 2 + 1] = p1;
                ad_out[d * 2 + 0] = p2; ad_out[d * 2 + 1] = p3;
            }
        }
    }
}

// ---------------- MFMA flash cross-attention v6 ----------------
__global__ __launch_bounds__(256, 4) void attn6_k(const __bf16* __restrict__ Qb,
    const __bf16* __restrict__ Ktab, const __bf16* __restrict__ Vtab,
    const unsigned short* __restrict__ tid16, __bf16* __restrict__ O)
{
    __shared__ __bf16 Ks[2][4096];
    __shared__ __bf16 Vs[4096];
    __shared__ __bf16 Ps2[4][16][64];
    __shared__ float mask_f[1024];
    __shared__ unsigned short tids[1024];
    const int t = threadIdx.x;
    const int bid = blockIdx.x;
    const int h = (bid >> 1) & 3;
    const int b = ((bid >> 3) << 1) | (bid & 1);
    const int w = t >> 6, lane = t & 63;
    const int quad = lane >> 4, l16 = lane & 15;
    const int key = (l16 & 7) << 4;
    const __bf16* Kh = Ktab + (size_t)h * NTAB * 64;
    const __bf16* Vh = Vtab + (size_t)h * NTAB * 64;
    {
        const uint32_t* src = (const uint32_t*)(tid16 + (size_t)b * LPN);
        uint32_t v0 = src[t], v1 = src[t + 256];
        ((uint32_t*)tids)[t] = v0;
        ((uint32_t*)tids)[t + 256] = v1;
        mask_f[2 * t + 0] = (v0 & 0x8000u) ? -1e9f : 0.f;
        mask_f[2 * t + 1] = (v0 & 0x80000000u) ? -1e9f : 0.f;
        mask_f[2 * (t + 256) + 0] = (v1 & 0x8000u) ? -1e9f : 0.f;
        mask_f[2 * (t + 256) + 1] = (v1 & 0x80000000u) ? -1e9f : 0.f;
    }
    const __bf16* qrow = Qb + (size_t)(b * 64 + w * 16 + l16) * HID + h * HD;
    bf16x8 aq0 = *(const bf16x8*)(qrow + quad * 8);
    bf16x8 aq1 = *(const bf16x8*)(qrow + 32 + quad * 8);
    __syncthreads();

    auto stageK = [&](int kt, int bufb) {
#pragma unroll
        for (int it = 0; it < 2; it++) {
            const int s = it * 256 + t;
            const int pos = s >> 3;
            const int c = (s & 7) ^ (pos & 7);
            const int row = tids[kt * 64 + pos] & 0x7fff;
            gl2lds16(Kh + (size_t)row * 64 + c * 8,
                     &Ks[bufb][(it * 256 + w * 64) * 8]);
        }
    };
    auto loadV = [&](int kt, bf16x8* vrr) {
#pragma unroll
        for (int it = 0; it < 2; it++) {
            const int pos = w * 8 + (lane >> 3) + it * 32;
            const int row = tids[kt * 64 + pos] & 0x7fff;
            vrr[it] = *(const bf16x8*)(Vh + (size_t)row * 64 + (lane & 7) * 8);
        }
    };
    auto writeV = [&](const bf16x8* vrr) {
        const int p = lane >> 3, c = lane & 7;
#pragma unroll
        for (int it = 0; it < 2; it++) {
            const int pos = w * 8 + p + it * 32;
            const int cp = pos >> 3;
#pragma unroll
            for (int j = 0; j < 8; j++) {
                const int chl = c * 8 + j;
                Vs[chl * 64 + (((cp ^ c ^ j) & 7) << 3) + p] = vrr[it][j];
            }
        }
    };

    bf16x8 vr[2];
    stageK(0, 0);
    loadV(0, vr);
    writeV(vr);
    float m_run = -3e38f;
    float l_run = 0.f;
    floatx4 ctx[4] = {};
    __syncthreads();

    for (int kt = 0; kt < 16; kt++) {
        const int buf = kt & 1;
        const int kp0 = kt * 64;
        if (kt < 15) {
            stageK(kt + 1, buf ^ 1);
            loadV(kt + 1, vr);
        }
        const int ksl0 = (quad ^ (l16 & 7)) * 8;
        const int ksl1 = ((quad + 4) ^ (l16 & 7)) * 8;
        floatx4 s[4];
#pragma unroll
        for (int nj = 0; nj < 4; nj++) {
            const __bf16* kr = &Ks[buf][(nj * 16 + l16) * 64];
            bf16x8 k0 = *(const bf16x8*)&kr[ksl0];
            bf16x8 k1 = *(const bf16x8*)&kr[ksl1];
            floatx4 z = {0.f, 0.f, 0.f, 0.f};
            s[nj] = __builtin_amdgcn_mfma_f32_16x16x32_bf16(k0, aq0, z, 0, 0, 0);
            s[nj] = __builtin_amdgcn_mfma_f32_16x16x32_bf16(k1, aq1, s[nj], 0, 0, 0);
        }
#pragma unroll
        for (int nj = 0; nj < 4; nj++) {
            floatx4 m4 = *(const floatx4*)&mask_f[kp0 + nj * 16 + quad * 4];
#pragma unroll
            for (int r = 0; r < 4; r++) s[nj][r] += m4[r];
        }
        float mx = -3e38f;
#pragma unroll
        for (int nj = 0; nj < 4; nj++)
#pragma unroll
            for (int r = 0; r < 4; r++) mx = fmaxf(mx, s[nj][r]);
        mx = fmaxf(mx, __shfl_xor(mx, 16, 64));
        mx = fmaxf(mx, __shfl_xor(mx, 32, 64));
        const float mn = fmaxf(m_run, mx);
        const float alpha = __expf(m_run - mn);
        m_run = mn;
        float rs = 0.f;
#pragma unroll
        for (int nj = 0; nj < 4; nj++)
#pragma unroll
            for (int r = 0; r < 4; r++) {
                float p = __expf(s[nj][r] - mn);
                s[nj][r] = p;
                rs += p;
            }
        rs += __shfl_xor(rs, 16, 64);
        rs += __shfl_xor(rs, 32, 64);
        l_run = l_run * alpha + rs;
        float al[4];
#pragma unroll
        for (int r = 0; r < 4; r++) al[r] = __shfl(alpha, quad * 4 + r, 64);
        {
            char* rowp = (char*)&Ps2[w][l16][0];
#pragma unroll
            for (int nj = 0; nj < 4; nj++) {
                union { uint2 u2; unsigned short us[4]; } pk;
#pragma unroll
                for (int r = 0; r < 4; r++) {
                    __bf16 bv = (__bf16)s[nj][r];
                    pk.us[r] = *(unsigned short*)&bv;
                }
                *(uint2*)(rowp + ((nj * 32 + quad * 8) ^ key)) = pk.u2;
            }
        }
        bf16x8 pa0 = *(const bf16x8*)((char*)&Ps2[w][l16][0] + ((quad * 16) ^ key));
        bf16x8 pa1 = *(const bf16x8*)((char*)&Ps2[w][l16][0] + ((64 + quad * 16) ^ key));
#pragma unroll
        for (int dj = 0; dj < 4; dj++) {
#pragma unroll
            for (int r = 0; r < 4; r++) ctx[dj][r] *= al[r];
            const int chl = dj * 16 + l16;
            const int Xc = ((chl >> 3) ^ (chl & 7)) & 7;
            bf16x8 bv0 = *(const bf16x8*)&Vs[chl * 64 + (((quad ^ Xc) & 7) << 3)];
            bf16x8 bv1 = *(const bf16x8*)&Vs[chl * 64 + ((((quad + 4) ^ Xc) & 7) << 3)];
            ctx[dj] = __builtin_amdgcn_mfma_f32_16x16x32_bf16(pa0, bv0, ctx[dj], 0, 0, 0);
            ctx[dj] = __builtin_amdgcn_mfma_f32_16x16x32_bf16(pa1, bv1, ctx[dj], 0, 0, 0);
        }
        __syncthreads();
        if (kt < 15) writeV(vr);
        __syncthreads();
    }
    float ll[4];
#pragma unroll
    for (int r = 0; r < 4; r++) ll[r] = __shfl(l_run, quad * 4 + r, 64);
#pragma unroll
    for (int dj = 0; dj < 4; dj++)
#pragma unroll
        for (int r = 0; r < 4; r++) {
            int q = w * 16 + quad * 4 + r;
            O[((size_t)(b * 64 + q)) * 256 + h * HD + dj * 16 + l16] = (__bf16)(ctx[dj][r] / ll[r]);
        }
}

// ---------------- LayerNorm(residual) ----------------
__device__ __forceinline__ float blockSum256(float v, float* red)
{
#pragma unroll
    for (int off = 32; off >= 1; off >>= 1) v += __shfl_down(v, off, 64);
    int wave = threadIdx.x >> 6, lane = threadIdx.x & 63;
    if (lane == 0) red[wave] = v;
    __syncthreads();
    float s = red[0] + red[1] + red[2] + red[3];
    __syncthreads();
    return s;
}

__global__ __launch_bounds__(256) void lnres_k(const float* __restrict__ A,
    const float* __restrict__ Bb, const float* __restrict__ g,
    const float* __restrict__ be, float* __restrict__ Y, __bf16* __restrict__ Yb)
{
    __shared__ float red[4];
    int r = blockIdx.x, t = threadIdx.x;
    float v = A[(size_t)r * 256 + t] + Bb[(size_t)r * 256 + t];
    float mean = blockSum256(v, red) * (1.f / 256.f);
    float d = v - mean;
    float var = blockSum256(d * d, red) * (1.f / 256.f);
    float o = d * rsqrtf(var + 1e-5f) * g[t] + be[t];
    Y[(size_t)r * 256 + t] = o;
    if (Yb) Yb[(size_t)r * 256 + t] = (__bf16)o;
}

// ---------------- fused tail: LN2(residual) + mean-pool + fc1 + fc2 ----------
__global__ __launch_bounds__(256) void head2_k(const float* __restrict__ A,
    const float* __restrict__ Bb, const float* __restrict__ g,
    const float* __restrict__ be,
    const float* __restrict__ fc1w, const float* __restrict__ fc1b,
    const float* __restrict__ fc2w, const float* __restrict__ fc2b,
    float* __restrict__ out)
{
    __shared__ float pooled4[4][256];
    __shared__ float pooled[256];
    __shared__ float h[256];
    __shared__ float red[4];
    const int b = blockIdx.x, t = threadIdx.x;
    const int wv = t >> 6, lane = t & 63;
    const int ch = lane * 4;
    float g0 = g[ch], g1 = g[ch + 1], g2 = g[ch + 2], g3 = g[ch + 3];
    float b0 = be[ch], b1v = be[ch + 1], b2v = be[ch + 2], b3v = be[ch + 3];
    float accp0 = 0.f, accp1 = 0.f, accp2 = 0.f, accp3 = 0.f;
    for (int r = wv; r < 64; r += 4) {
        const size_t base = (size_t)(b * 64 + r) * 256 + ch;
        float v0 = A[base + 0] + Bb[base + 0];
        float v1 = A[base + 1] + Bb[base + 1];
        float v2 = A[base + 2] + Bb[base + 2];
        float v3 = A[base + 3] + Bb[base + 3];
        float s = v0 + v1 + v2 + v3;
#pragma unroll
        for (int off = 32; off >= 1; off >>= 1) s += __shfl_xor(s, off, 64);
        float mean = s * (1.f / 256.f);
        float c0 = v0 - mean, c1 = v1 - mean, c2 = v2 - mean, c3 = v3 - mean;
        float s2 = c0 * c0 + c1 * c1 + c2 * c2 + c3 * c3;
#pragma unroll
        for (int off = 32; off >= 1; off >>= 1) s2 += __shfl_xor(s2, off, 64);
        float rstd = rsqrtf(s2 * (1.f / 256.f) + 1e-5f);
        accp0 += c0 * rstd * g0 + b0;
        accp1 += c1 * rstd * g1 + b1v;
        accp2 += c2 * rstd * g2 + b2v;
        accp3 += c3 * rstd * g3 + b3v;
    }
    pooled4[wv][ch + 0] = accp0;
    pooled4[wv][ch + 1] = accp1;
    pooled4[wv][ch + 2] = accp2;
    pooled4[wv][ch + 3] = accp3;
    __syncthreads();
    pooled[t] = (pooled4[0][t] + pooled4[1][t] + pooled4[2][t] + pooled4[3][t])
                / (64.f + 1e-6f);
    __syncthreads();
    float a = 0.f;
    for (int k = 0; k < 256; k += 4) {
        a += pooled[k + 0] * fc1w[(k + 0) * 256 + t];
        a += pooled[k + 1] * fc1w[(k + 1) * 256 + t];
        a += pooled[k + 2] * fc1w[(k + 2) * 256 + t];
        a += pooled[k + 3] * fc1w[(k + 3) * 256 + t];
    }
    h[t] = fmaxf(a + fc1b[t], 0.f);
    __syncthreads();
    float p = h[t] * fc2w[t];
    p = blockSum256(p, red);
    if (t == 0) out[b] = p + fc2b[0];
}

// ---------------- launch ----------------
extern "C" void kernel_launch(void* const* d_in, const int* in_sizes, int n_in,
                              void* d_out, int out_size, void* d_ws, size_t ws_size,
                              hipStream_t stream)
{
    const float* x     = (const float*)d_in[0];
    const int*   ei    = (const int*)d_in[1];
    const int*   pseq  = (const int*)d_in[3];
    const float* w1  = (const float*)d_in[4];
    const float* as1 = (const float*)d_in[5];
    const float* ad1 = (const float*)d_in[6];
    const float* b1  = (const float*)d_in[7];
    const float* w2  = (const float*)d_in[8];
    const float* as2 = (const float*)d_in[9];
    const float* ad2 = (const float*)d_in[10];
    const float* b2  = (const float*)d_in[11];
    const float* w3  = (const float*)d_in[12];
    const float* as3 = (const float*)d_in[13];
    const float* ad3 = (const float*)d_in[14];
    const float* b3  = (const float*)d_in[15];
    const float* emb    = (const float*)d_in[16];
    const float* conv_w = (const float*)d_in[17];
    const float* conv_b = (const float*)d_in[18];
    const float* wq = (const float*)d_in[19];
    const float* bq = (const float*)d_in[20];
    const float* wk = (const float*)d_in[21];
    const float* bk = (const float*)d_in[22];
    const float* wv = (const float*)d_in[23];
    const float* bv = (const float*)d_in[24];
    const float* wo = (const float*)d_in[25];
    const float* bo = (const float*)d_in[26];
    const float* ln1_g = (const float*)d_in[27];
    const float* ln1_b = (const float*)d_in[28];
    const float* ffw1  = (const float*)d_in[29];
    const float* ffb1  = (const float*)d_in[30];
    const float* ffw2  = (const float*)d_in[31];
    const float* ffb2  = (const float*)d_in[32];
    const float* ln2_g = (const float*)d_in[33];
    const float* ln2_b = (const float*)d_in[34];
    const float* fc1_w = (const float*)d_in[35];
    const float* fc1_b = (const float*)d_in[36];
    const float* fc2_w = (const float*)d_in[37];
    const float* fc2_b = (const float*)d_in[38];
    (void)in_sizes; (void)n_in; (void)out_size;

    char* ws = (char*)d_ws;
    size_t off = 0;
    auto alloc = [&](size_t bytes) -> char* {
        char* p = ws + off;
        off += (bytes + 255) & ~(size_t)255;
        return p;
    };
    // ---- fixed arena ----
    __bf16* hgb  = (__bf16*)alloc((size_t)NAT * 512 * 2);
    float* og    = (float*)alloc((size_t)NAT * 512 * 4);
    float* hb0   = (float*)alloc((size_t)NAT * 256 * 4);
    float* hb1   = (float*)alloc((size_t)NAT * 256 * 4);
    __bf16* xb   = (__bf16*)alloc((size_t)NAT * FIN * 2);
    __bf16* hbb  = (__bf16*)alloc((size_t)NAT * 256 * 2);
    __bf16* qbb  = (__bf16*)alloc((size_t)NAT * 256 * 2);
    __bf16* ctxbb= (__bf16*)alloc((size_t)NAT * 256 * 2);
    __bf16* ybb  = (__bf16*)alloc((size_t)NAT * 256 * 2);
    float* asA   = (float*)alloc((size_t)NAT * 2 * 4);
    float* adA   = (float*)alloc((size_t)NAT * 2 * 4);
    float* asB   = (float*)alloc((size_t)NAT * 2 * 4);
    float* adB   = (float*)alloc((size_t)NAT * 2 * 4);
    float* wasd  = (float*)alloc((size_t)3 * 256 * 4 * 4);
    int* deg     = (int*)alloc((size_t)NAT * 4);
    int* fill    = (int*)alloc((size_t)NAT * 4);
    int* rowptr  = (int*)alloc((size_t)(NAT + 1) * 4);
    int* csrc    = (int*)alloc((size_t)NED * 4);
    int* cdst    = (int*)alloc((size_t)NED * 4);
    float* tap   = (float*)alloc((size_t)3 * 22 * 256 * 4);
    __bf16* ptab = (__bf16*)alloc((size_t)NTAB * 256 * 2);
    __bf16* Ktab = (__bf16*)alloc((size_t)NTAB * 256 * 2);   // [4][NTAB][64]
    __bf16* Vtab = (__bf16*)alloc((size_t)NTAB * 256 * 2);   // [4][NTAB][64]
    unsigned short* tid16 = (unsigned short*)alloc((size_t)BGR * LPN * 2);
    __bf16* w1T  = (__bf16*)alloc((size_t)512 * 64 * 2);
    __bf16* w2T  = (__bf16*)alloc((size_t)512 * 256 * 2);
    __bf16* w3T  = (__bf16*)alloc((size_t)512 * 256 * 2);
    __bf16* wkT  = (__bf16*)alloc((size_t)256 * 256 * 2);
    __bf16* wvT  = (__bf16*)alloc((size_t)256 * 256 * 2);
    __bf16* wqT  = (__bf16*)alloc((size_t)256 * 256 * 2);
    __bf16* woT  = (__bf16*)alloc((size_t)256 * 256 * 2);
    __bf16* f1T  = (__bf16*)alloc((size_t)1024 * 256 * 2);
    __bf16* f2T  = (__bf16*)alloc((size_t)256 * 1024 * 2);
    // ---- variable region (FF intermediates) ----
    size_t fixed_end = off;
    char* region   = ws + fixed_end;
    __bf16* ffbb   = (__bf16*)region;
    float* attno = og;
    float* ybuf  = og + (size_t)NAT * 256;
    float* ff2o  = hb1;
    (void)ws_size;

    // ---------------- zero deg/fill ----------------
    hipMemsetAsync(deg, 0, (size_t)NAT * 8, stream);   // deg + fill (adjacent)

    // ---------------- fused preamble 1 ----------------
    {
        Segs S;
        const float* srcs[10] = {x, w1, w2, w3, wk, wv, wq, wo, ffw1, ffw2};
        __bf16* dsts[10] = {xb, w1T, w2T, w3T, wkT, wvT, wqT, woT, f1T, f2T};
        int kd[10] = {0, 64, 256, 256, 256, 256, 256, 256, 256, 1024};
        int nd[10] = {0, 512, 512, 512, 256, 256, 256, 256, 1024, 256};
        int md[10] = {0, 1, 1, 1, 1, 1, 1, 1, 1, 1};
        int cnt[10] = {NAT * FIN, 32768, 131072, 131072,
                       65536, 65536, 65536, 65536, 262144, 262144};
        int run = 0;
        for (int i = 0; i < 10; i++) {
            S.src[i] = srcs[i]; S.dst[i] = dsts[i];
            S.kdim[i] = kd[i]; S.ndim[i] = nd[i]; S.mode[i] = md[i];
            S.start[i] = run; run += cnt[i];
        }
        S.start[10] = run; S.start[11] = run; S.start[12] = run;
        int grid1 = 1349 + (run + 255) / 256;
        misc1_k<<<grid1, 256, 0, stream>>>(ei, deg, emb, conv_w, tap, pseq, tid16,
                                           w1, w2, w3, as1, as2, as3, ad1, ad2, ad3,
                                           wasd, S, run);
    }

    // ---------------- fused preamble 2: scan + ptab ----------------
    misc2_k<<<1 + NTAB / 8, 256, 0, stream>>>(deg, rowptr, tap, conv_b, ptab);

    // ---------------- fused preamble 3: scat + kvtab + layer0 a_s ------------
    misc3_k<<<128 + 4 * (NTAB / 128) + NAT / 64, 512, 0, stream>>>(
        ei, fill, rowptr, csrc, cdst, ptab, wkT, wvT, bk, bv, Ktab, Vtab,
        xb, wasd, asA, adA);

    // ---------------- ligand GNN: 3 GAT layers ----------------
    const __bf16* WT[3] = {w1T, w2T, w3T};
    const float* bl[3]  = {b1, b2, b3};
    float* houts[3] = {nullptr, nullptr, hb0};
    const float* asr[3] = {asA, asB, asA};
    const float* adr[3] = {adA, adB, adA};
    float* asw[3] = {asB, asA, nullptr};
    float* adw[3] = {adB, adA, nullptr};
    const __bf16* hinb = xb;
    int Kdim = FIN;
    for (int l = 0; l < 3; l++) {
        gemm_gat<<<dim3(4, NAT / 128), 512, 0, stream>>>(hinb, WT[l], hgb, Kdim);
        const float* wnext = (l < 2) ? (wasd + (size_t)(l + 1) * 256 * 4) : nullptr;
        gat_agg<<<NAT / 4, 256, 0, stream>>>(rowptr, csrc, hgb, asr[l], adr[l],
                                             bl[l], wnext, asw[l], adw[l],
                                             houts[l], hbb);
        hinb = hbb;
        Kdim = HID;
    }
    const float* lig = hb0;
    const __bf16* ligb = hbb;

    // ---------------- Q projection (scale 1/8 folded in), 64-col tiles -------
    gemm_mfma<0, 1, 0, 0, 64><<<dim3(4, NAT / 128), 512, 0, stream>>>(ligb, wqT, bq, qbb, NAT, 256, 256, 0.125f);

    // ---------------- cross-attention: single dispatch ----------------
    attn6_k<<<BGR * 4, 256, 0, stream>>>(qbb, Ktab, Vtab, tid16, ctxbb);

    // ---------------- attention out proj + LN + FFN + fused tail -------------
    gemm_mfma<0, 0, 0, 0, 64><<<dim3(4, NAT / 128), 512, 0, stream>>>(ctxbb, woT, bo, attno, NAT, 256, 256, 1.f);
    lnres_k<<<NAT, 256, 0, stream>>>(lig, attno, ln1_g, ln1_b, ybuf, ybb);
    gemm_mfma<2, 1, 0, 0, 128><<<dim3(8, NAT / 128), 512, 0, stream>>>(ybb, f1T, ffb1, ffbb, NAT, 1024, 256, 1.f);
    gemm_mfma<0, 0, 0, 0, 64><<<dim3(4, NAT / 128), 512, 0, stream>>>(ffbb, f2T, ffb2, ff2o, NAT, 256, 1024, 1.f);
    head2_k<<<BGR, 256, 0, stream>>>(ybuf, ff2o, ln2_g, ln2_b,
                                     fc1_w, fc1_b, fc2_w, fc2_b, (float*)d_out);
}

// Round 13
// 466.751 us; speedup vs baseline: 1.0408x; 1.0408x over previous
//
#include <hip/hip_runtime.h>
#include <hip/hip_bf16.h>
#include <cstdint>
#include <cstddef>

#define NAT 16384
#define NED 65536
#define BGR 256
#define FIN 64
#define HID 256
#define LPN 1024
#define HD 64
#define NTRIP 11638          // 23*22*23 distinct (t0,t1,t2) conv triples
#define NTAB  11648          // padded to multiple of 128 for MFMA tiles

typedef __bf16 bf16x8 __attribute__((ext_vector_type(8)));
typedef float floatx4 __attribute__((ext_vector_type(4)));

// async global->LDS 16B; dest = wave-uniform base + lane*16 (linear layout!)
__device__ __forceinline__ void gl2lds16(const void* g, void* l)
{
    __builtin_amdgcn_global_load_lds(
        (const __attribute__((address_space(1))) unsigned int*)g,
        (__attribute__((address_space(3))) unsigned int*)l, 16, 0, 0);
}

// ---------------- bf16 MFMA GEMM, 8-wave, BK=64 double sub-buffer ------------
template<int ACT, int OUTBF16, int BIASROW, int HSPLIT, int NCOL>
__global__ __launch_bounds__(512) void gemm_mfma(const __bf16* __restrict__ A,
    const __bf16* __restrict__ Bt, const float* __restrict__ bias,
    void* __restrict__ Cout, int M, int Nn, int K, float escale)
{
    constexpr int NJ = NCOL / 32;
    __shared__ __bf16 As[2][128][32];
    __shared__ __bf16 Bs[2][NCOL][32];
    const int t = threadIdx.x;
    const int m0 = blockIdx.y * 128, n0 = blockIdx.x * NCOL;
    const int w = t >> 6, lane = t & 63;
    const int wm = (w & 3) * 32, wn = (w >> 2) * (NCOL / 2);
    const int quad = lane >> 4, l16 = lane & 15;
    const int r0 = t >> 2, s0 = t & 3, g0 = (s0 ^ (r0 & 3)) * 8;
    const int fso = (quad ^ (l16 & 3)) * 8;
    floatx4 acc[2][NJ] = {};
    for (int k0 = 0; k0 < K; k0 += 64) {
        gl2lds16(A + (size_t)(m0 + r0) * K + k0 + g0,       &As[0][r0][s0 * 8]);
        gl2lds16(A + (size_t)(m0 + r0) * K + k0 + 32 + g0,  &As[1][r0][s0 * 8]);
        if (NCOL == 128 || t < 256) {
            gl2lds16(Bt + (size_t)(n0 + r0) * K + k0 + g0,      &Bs[0][r0][s0 * 8]);
            gl2lds16(Bt + (size_t)(n0 + r0) * K + k0 + 32 + g0, &Bs[1][r0][s0 * 8]);
        }
        __syncthreads();
#pragma unroll
        for (int c = 0; c < 2; c++) {
            bf16x8 af[2], bfr[NJ];
#pragma unroll
            for (int mi = 0; mi < 2; mi++) af[mi]  = *(const bf16x8*)&As[c][wm + mi * 16 + l16][fso];
#pragma unroll
            for (int nj = 0; nj < NJ; nj++) bfr[nj] = *(const bf16x8*)&Bs[c][wn + nj * 16 + l16][fso];
#pragma unroll
            for (int mi = 0; mi < 2; mi++)
#pragma unroll
                for (int nj = 0; nj < NJ; nj++)
                    acc[mi][nj] = __builtin_amdgcn_mfma_f32_16x16x32_bf16(af[mi], bfr[nj], acc[mi][nj], 0, 0, 0);
        }
        __syncthreads();
    }
#pragma unroll
    for (int mi = 0; mi < 2; mi++)
#pragma unroll
        for (int nj = 0; nj < NJ; nj++) {
            int col = n0 + wn + nj * 16 + l16;
#pragma unroll
            for (int r = 0; r < 4; r++) {
                int row = m0 + wm + mi * 16 + quad * 4 + r;
                float bval = bias ? (BIASROW ? bias[row] : bias[col]) : 0.f;
                float v = (acc[mi][nj][r] + bval) * escale;
                if (ACT == 1) v = fmaxf(v, 0.f);
                if (ACT == 2) v = 0.5f * v * (1.f + erff(v * 0.70710678118654752f));
                if (HSPLIT)      ((__bf16*)Cout)[((size_t)(col >> 6) * M + row) * 64 + (col & 63)] = (__bf16)v;
                else if (OUTBF16) ((__bf16*)Cout)[(size_t)row * Nn + col] = (__bf16)v;
                else              ((float*)Cout)[(size_t)row * Nn + col] = v;
            }
        }
}

// ---------------- GAT feature GEMM, BK=64: bf16 hg + partial a_s/a_d ---------
__global__ __launch_bounds__(512) void gemm_gat(const __bf16* __restrict__ A,
    const __bf16* __restrict__ Bt, const float* __restrict__ as_f,
    const float* __restrict__ ad_f, __bf16* __restrict__ Hg,
    float* __restrict__ part, int K)
{
    __shared__ __bf16 As[2][128][32];
    __shared__ __bf16 Bs[2][128][32];
    const int t = threadIdx.x;
    const int m0 = blockIdx.y * 128, n0 = blockIdx.x * 128;
    const int w = t >> 6, lane = t & 63;
    const int wm = (w & 3) * 32, wn = (w >> 2) * 64;
    const int quad = lane >> 4, l16 = lane & 15;
    const int r0 = t >> 2, s0 = t & 3, g0 = (s0 ^ (r0 & 3)) * 8;
    const int fso = (quad ^ (l16 & 3)) * 8;
    floatx4 acc[2][4] = {};
    for (int k0 = 0; k0 < K; k0 += 64) {
        gl2lds16(A + (size_t)(m0 + r0) * K + k0 + g0,       &As[0][r0][s0 * 8]);
        gl2lds16(A + (size_t)(m0 + r0) * K + k0 + 32 + g0,  &As[1][r0][s0 * 8]);
        gl2lds16(Bt + (size_t)(n0 + r0) * K + k0 + g0,      &Bs[0][r0][s0 * 8]);
        gl2lds16(Bt + (size_t)(n0 + r0) * K + k0 + 32 + g0, &Bs[1][r0][s0 * 8]);
        __syncthreads();
#pragma unroll
        for (int c = 0; c < 2; c++) {
            bf16x8 af[2], bfr[4];
#pragma unroll
            for (int mi = 0; mi < 2; mi++) af[mi]  = *(const bf16x8*)&As[c][wm + mi * 16 + l16][fso];
#pragma unroll
            for (int nj = 0; nj < 4; nj++) bfr[nj] = *(const bf16x8*)&Bs[c][wn + nj * 16 + l16][fso];
#pragma unroll
            for (int mi = 0; mi < 2; mi++)
#pragma unroll
                for (int nj = 0; nj < 4; nj++)
                    acc[mi][nj] = __builtin_amdgcn_mfma_f32_16x16x32_bf16(af[mi], bfr[nj], acc[mi][nj], 0, 0, 0);
        }
        __syncthreads();
    }
    const int slot = blockIdx.x * 2 + (w >> 2);
#pragma unroll
    for (int mi = 0; mi < 2; mi++) {
#pragma unroll
        for (int r = 0; r < 4; r++) {
            float ps = 0.f, pd = 0.f;
#pragma unroll
            for (int nj = 0; nj < 4; nj++) {
                int col = n0 + wn + nj * 16 + l16;
                float v = acc[mi][nj][r];
                ps += v * as_f[col];
                pd += v * ad_f[col];
            }
#pragma unroll
            for (int off = 1; off < 16; off <<= 1) {
                ps += __shfl_xor(ps, off, 64);
                pd += __shfl_xor(pd, off, 64);
            }
            if (l16 == 0) {
                int row = m0 + wm + mi * 16 + quad * 4 + r;
                part[(size_t)(slot * 2 + 0) * NAT + row] = ps;
                part[(size_t)(slot * 2 + 1) * NAT + row] = pd;
            }
        }
    }
#pragma unroll
    for (int mi = 0; mi < 2; mi++)
#pragma unroll
        for (int nj = 0; nj < 4; nj++) {
            int col = n0 + wn + nj * 16 + l16;
#pragma unroll
            for (int r = 0; r < 4; r++) {
                int row = m0 + wm + mi * 16 + quad * 4 + r;
                Hg[(size_t)row * 512 + col] = (__bf16)acc[mi][nj][r];
            }
        }
}

// fold 8 column-partials into a_s/a_d
__global__ void fold_k(const float* __restrict__ part, float* __restrict__ a_s,
                       float* __restrict__ a_d)
{
    int n = blockIdx.x * 256 + threadIdx.x;
    float s0 = 0.f, d0 = 0.f, s1 = 0.f, d1 = 0.f;
#pragma unroll
    for (int sl = 0; sl < 4; sl++) {
        s0 += part[(size_t)(sl * 2 + 0) * NAT + n];
        d0 += part[(size_t)(sl * 2 + 1) * NAT + n];
        s1 += part[(size_t)((sl + 4) * 2 + 0) * NAT + n];
        d1 += part[(size_t)((sl + 4) * 2 + 1) * NAT + n];
    }
    a_s[n * 2 + 0] = s0; a_s[n * 2 + 1] = s1;
    a_d[n * 2 + 0] = d0; a_d[n * 2 + 1] = d1;
}

// ---------------- single fused conversion kernel ----------------
struct Segs {
    const float* src[12];
    __bf16* dst[12];
    int kdim[12];
    int ndim[12];
    int mode[12];          // 0 copy, 1 transpose
    int start[13];
};

// ---------------- fused preamble 1: deg + tap + tid + cvtall -----------------
__global__ __launch_bounds__(256) void misc1_k(const int* __restrict__ ei,
    int* __restrict__ deg, const float* __restrict__ emb,
    const float* __restrict__ cw, float* __restrict__ tap,
    const int* __restrict__ seq, unsigned short* __restrict__ tid,
    Segs S, int total)
{
    const int bid = blockIdx.x;
    const int t = threadIdx.x;
    if (bid < 256) {
        int e = bid * 256 + t;
        atomicAdd(&deg[ei[NED + e]], 1);
    } else if (bid < 520) {
        const int b = bid - 256;
        const int dlv = b >> 2, part = b & 3;
        const int dl = dlv / 22, v = dlv % 22;
        const float* er = emb + v * 256 + part * 64;
        const float* wr = cw + (size_t)t * 768 + part * 192 + dl;
        float s = 0.f;
        for (int k = 0; k < 64; k += 4) {
            s += er[k + 0] * wr[k * 3 + 0];
            s += er[k + 1] * wr[k * 3 + 3];
            s += er[k + 2] * wr[k * 3 + 6];
            s += er[k + 3] * wr[k * 3 + 9];
        }
        atomicAdd(&tap[(size_t)dlv * 256 + t], s);
    } else if (bid < 1544) {
        int i = (bid - 520) * 256 + t;
        int b = i >> 10, l = i & 1023;
        const int* sr = seq + b * LPN;
        int t0 = (l > 0) ? sr[l - 1] : -1;
        int t1 = sr[l];
        int t2 = (l < LPN - 1) ? sr[l + 1] : -1;
        int v = (t0 + 1) * 506 + t1 * 23 + (t2 + 1);
        tid[i] = (unsigned short)(v | (t1 == 0 ? 0x8000 : 0));
    } else {
        int i = (bid - 1544) * 256 + t;
        if (i >= total) return;
        int s = 0;
        while (i >= S.start[s + 1]) s++;
        int j = i - S.start[s];
        if (S.mode[s] == 0) {
            S.dst[s][j] = (__bf16)S.src[s][j];
        } else {
            int K = S.kdim[s], N = S.ndim[s];
            int n = j / K, k = j - n * K;
            S.dst[s][j] = (__bf16)S.src[s][(size_t)k * N + n];
        }
    }
}

// ---------------- fused preamble 2: scan (block 0) + ptab --------------------
__global__ __launch_bounds__(256) void misc2_k(const int* __restrict__ deg,
    int* __restrict__ rowptr, const float* __restrict__ tap,
    const float* __restrict__ bias, __bf16* __restrict__ P)
{
    __shared__ int part[256];
    const int t = threadIdx.x;
    if (blockIdx.x == 0) {
        int base = t * 64;
        int s = 0;
#pragma unroll
        for (int i = 0; i < 64; i++) s += deg[base + i];
        part[t] = s;
        __syncthreads();
        for (int off = 1; off < 256; off <<= 1) {
            int v = (t >= off) ? part[t - off] : 0;
            __syncthreads();
            part[t] += v;
            __syncthreads();
        }
        int run = t ? part[t - 1] : 0;
        for (int i = 0; i < 64; i++) { rowptr[base + i] = run; run += deg[base + i]; }
        if (t == 255) rowptr[16384] = run;
    } else {
        const int row = (blockIdx.x - 1) * 8 + (t >> 5);
        const int c = (t & 31) * 8;
        __bf16 o[8];
        if (row < NTRIP) {
            const int a = row / 506, rem = row - a * 506;
            const int t1 = rem / 23, c2 = rem - t1 * 23;
            float acc[8];
#pragma unroll
            for (int j = 0; j < 8; j++) acc[j] = bias[c + j];
            if (a > 0) {
                const float* r = tap + (size_t)(0 * 22 + (a - 1)) * 256 + c;
#pragma unroll
                for (int j = 0; j < 8; j++) acc[j] += r[j];
            }
            {
                const float* r = tap + (size_t)(1 * 22 + t1) * 256 + c;
#pragma unroll
                for (int j = 0; j < 8; j++) acc[j] += r[j];
            }
            if (c2 > 0) {
                const float* r = tap + (size_t)(2 * 22 + (c2 - 1)) * 256 + c;
#pragma unroll
                for (int j = 0; j < 8; j++) acc[j] += r[j];
            }
#pragma unroll
            for (int j = 0; j < 8; j++) o[j] = (__bf16)fmaxf(acc[j], 0.f);
        } else {
#pragma unroll
            for (int j = 0; j < 8; j++) o[j] = (__bf16)0.f;
        }
        *(uint4*)(P + (size_t)row * 256 + c) = *(uint4*)o;
    }
}

// ---------------- fused preamble 3: scat (blocks 0..127) + kvtab -------------
__global__ __launch_bounds__(512) void misc3_k(const int* __restrict__ ei,
    int* __restrict__ fill, const int* __restrict__ rowptr,
    int* __restrict__ csrc, int* __restrict__ cdst,
    const __bf16* __restrict__ A, const __bf16* __restrict__ wkT,
    const __bf16* __restrict__ wvT, const float* __restrict__ bk,
    const float* __restrict__ bv, __bf16* __restrict__ Ktab,
    __bf16* __restrict__ Vtab)
{
    __shared__ __bf16 As[2][128][32];
    __shared__ __bf16 Bs[2][128][32];
    const int t = threadIdx.x;
    if (blockIdx.x < 128) {
        int e = blockIdx.x * 512 + t;
        if (e >= NED) return;
        int d = ei[NED + e];
        int pos = rowptr[d] + atomicAdd(&fill[d], 1);
        csrc[pos] = ei[e];
        cdst[pos] = d;
        return;
    }
    const int lb = blockIdx.x - 128;
    const int bx = lb & 3, by = lb >> 2;
    const int z = bx >> 1;
    const int m0 = by * 128, n0 = (bx & 1) * 128;
    const __bf16* Bt = z ? wvT : wkT;
    const float* bias = z ? bv : bk;
    __bf16* Cout = z ? Vtab : Ktab;
    const int w = t >> 6, lane = t & 63;
    const int wm = (w & 3) * 32, wn = (w >> 2) * 64;
    const int quad = lane >> 4, l16 = lane & 15;
    const int r0 = t >> 2, s0 = t & 3, g0 = (s0 ^ (r0 & 3)) * 8;
    const int fso = (quad ^ (l16 & 3)) * 8;
    floatx4 acc[2][4] = {};
    for (int k0 = 0; k0 < 256; k0 += 64) {
        gl2lds16(A + (size_t)(m0 + r0) * 256 + k0 + g0,       &As[0][r0][s0 * 8]);
        gl2lds16(A + (size_t)(m0 + r0) * 256 + k0 + 32 + g0,  &As[1][r0][s0 * 8]);
        gl2lds16(Bt + (size_t)(n0 + r0) * 256 + k0 + g0,      &Bs[0][r0][s0 * 8]);
        gl2lds16(Bt + (size_t)(n0 + r0) * 256 + k0 + 32 + g0, &Bs[1][r0][s0 * 8]);
        __syncthreads();
#pragma unroll
        for (int c = 0; c < 2; c++) {
            bf16x8 af[2], bfr[4];
#pragma unroll
            for (int mi = 0; mi < 2; mi++) af[mi]  = *(const bf16x8*)&As[c][wm + mi * 16 + l16][fso];
#pragma unroll
            for (int nj = 0; nj < 4; nj++) bfr[nj] = *(const bf16x8*)&Bs[c][wn + nj * 16 + l16][fso];
#pragma unroll
            for (int mi = 0; mi < 2; mi++)
#pragma unroll
                for (int nj = 0; nj < 4; nj++)
                    acc[mi][nj] = __builtin_amdgcn_mfma_f32_16x16x32_bf16(af[mi], bfr[nj], acc[mi][nj], 0, 0, 0);
        }
        __syncthreads();
    }
#pragma unroll
    for (int mi = 0; mi < 2; mi++)
#pragma unroll
        for (int nj = 0; nj < 4; nj++) {
            int col = n0 + wn + nj * 16 + l16;
#pragma unroll
            for (int r = 0; r < 4; r++) {
                int row = m0 + wm + mi * 16 + quad * 4 + r;
                float v = acc[mi][nj][r] + bias[col];
                Cout[((size_t)(col >> 6) * NTAB + row) * 64 + (col & 63)] = (__bf16)v;
            }
        }
}

// ---------------- fused GAT aggregation (e recomputed inline, no erec) -------
__global__ __launch_bounds__(256) void gat_agg(const int* __restrict__ rowptr,
    const int* __restrict__ csrc, const __bf16* __restrict__ hgb,
    const float* __restrict__ a_s, const float* __restrict__ a_d,
    const float* __restrict__ bias, float* __restrict__ out, __bf16* __restrict__ outb)
{
    const int wave = threadIdx.x >> 6, lane = threadIdx.x & 63;
    const int d = blockIdx.x * 4 + wave;
    const int beg = rowptr[d], end = rowptr[d + 1];
    float2 as2 = *(const float2*)(a_s + d * 2);
    float2 ad2 = *(const float2*)(a_d + d * 2);
    float e0 = as2.x + ad2.x; e0 = (e0 > 0.f) ? e0 : 0.2f * e0;
    float e1 = as2.y + ad2.y; e1 = (e1 > 0.f) ? e1 : 0.2f * e1;
    float m0 = e0, den0 = 1.f, m1 = e1, den1 = 1.f;
    for (int p = beg; p < end; p++) {
        int s = csrc[p];
        float2 av = *(const float2*)(a_s + s * 2);
        float f0 = av.x + ad2.x; f0 = (f0 > 0.f) ? f0 : 0.2f * f0;
        float f1 = av.y + ad2.y; f1 = (f1 > 0.f) ? f1 : 0.2f * f1;
        float nm0 = fmaxf(m0, f0);
        den0 = den0 * __expf(m0 - nm0) + __expf(f0 - nm0);
        m0 = nm0;
        float nm1 = fmaxf(m1, f1);
        den1 = den1 * __expf(m1 - nm1) + __expf(f1 - nm1);
        m1 = nm1;
    }
    const float inv0 = 1.f / den0, inv1 = 1.f / den1;
    const int ch = lane * 8;
    const int g = ch >> 8;
    const float mg = g ? m1 : m0, invg = g ? inv1 : inv0;
    float acc[8] = {};
    {
        float al = __expf((g ? e1 : e0) - mg) * invg;
        bf16x8 hv = *(const bf16x8*)(hgb + (size_t)d * 512 + ch);
#pragma unroll
        for (int j = 0; j < 8; j++) acc[j] += (float)hv[j] * al;
    }
    for (int p = beg; p < end; p++) {
        int s = csrc[p];
        float2 av = *(const float2*)(a_s + s * 2);
        float f0 = av.x + ad2.x; f0 = (f0 > 0.f) ? f0 : 0.2f * f0;
        float f1 = av.y + ad2.y; f1 = (f1 > 0.f) ? f1 : 0.2f * f1;
        float al = __expf((g ? f1 : f0) - mg) * invg;
        bf16x8 hv = *(const bf16x8*)(hgb + (size_t)s * 512 + ch);
#pragma unroll
        for (int j = 0; j < 8; j++) acc[j] += (float)hv[j] * al;
    }
    float other[8];
#pragma unroll
    for (int j = 0; j < 8; j++) other[j] = __shfl_xor(acc[j], 32, 64);
    if (lane < 32) {
#pragma unroll
        for (int j = 0; j < 8; j++) {
            float v = 0.5f * (acc[j] + other[j]) + bias[ch + j];
            v = (v > 0.f) ? v : expm1f(v);
            if (out) out[(size_t)d * 256 + ch + j] = v;
            outb[(size_t)d * 256 + ch + j] = (__bf16)v;
        }
    }
}

// ---------------- MFMA flash cross-attention v6 ----------------
__global__ __launch_bounds__(256, 4) void attn6_k(const __bf16* __restrict__ Qb,
    const __bf16* __restrict__ Ktab, const __bf16* __restrict__ Vtab,
    const unsigned short* __restrict__ tid16, __bf16* __restrict__ O)
{
    __shared__ __bf16 Ks[2][4096];
    __shared__ __bf16 Vs[4096];
    __shared__ __bf16 Ps2[4][16][64];
    __shared__ float mask_f[1024];
    __shared__ unsigned short tids[1024];
    const int t = threadIdx.x;
    const int bid = blockIdx.x;
    const int h = (bid >> 1) & 3;
    const int b = ((bid >> 3) << 1) | (bid & 1);
    const int w = t >> 6, lane = t & 63;
    const int quad = lane >> 4, l16 = lane & 15;
    const int key = (l16 & 7) << 4;
    const __bf16* Kh = Ktab + (size_t)h * NTAB * 64;
    const __bf16* Vh = Vtab + (size_t)h * NTAB * 64;
    {
        const uint32_t* src = (const uint32_t*)(tid16 + (size_t)b * LPN);
        uint32_t v0 = src[t], v1 = src[t + 256];
        ((uint32_t*)tids)[t] = v0;
        ((uint32_t*)tids)[t + 256] = v1;
        mask_f[2 * t + 0] = (v0 & 0x8000u) ? -1e9f : 0.f;
        mask_f[2 * t + 1] = (v0 & 0x80000000u) ? -1e9f : 0.f;
        mask_f[2 * (t + 256) + 0] = (v1 & 0x8000u) ? -1e9f : 0.f;
        mask_f[2 * (t + 256) + 1] = (v1 & 0x80000000u) ? -1e9f : 0.f;
    }
    const __bf16* qrow = Qb + (size_t)(b * 64 + w * 16 + l16) * HID + h * HD;
    bf16x8 aq0 = *(const bf16x8*)(qrow + quad * 8);
    bf16x8 aq1 = *(const bf16x8*)(qrow + 32 + quad * 8);
    __syncthreads();

    auto stageK = [&](int kt, int bufb) {
#pragma unroll
        for (int it = 0; it < 2; it++) {
            const int s = it * 256 + t;
            const int pos = s >> 3;
            const int c = (s & 7) ^ (pos & 7);
            const int row = tids[kt * 64 + pos] & 0x7fff;
            gl2lds16(Kh + (size_t)row * 64 + c * 8,
                     &Ks[bufb][(it * 256 + w * 64) * 8]);
        }
    };
    auto loadV = [&](int kt, bf16x8* vrr) {
#pragma unroll
        for (int it = 0; it < 2; it++) {
            const int pos = w * 8 + (lane >> 3) + it * 32;
            const int row = tids[kt * 64 + pos] & 0x7fff;
            vrr[it] = *(const bf16x8*)(Vh + (size_t)row * 64 + (lane & 7) * 8);
        }
    };
    auto writeV = [&](const bf16x8* vrr) {
        const int p = lane >> 3, c = lane & 7;
#pragma unroll
        for (int it = 0; it < 2; it++) {
            const int pos = w * 8 + p + it * 32;
            const int cp = pos >> 3;
#pragma unroll
            for (int j = 0; j < 8; j++) {
                const int chl = c * 8 + j;
                Vs[chl * 64 + (((cp ^ c ^ j) & 7) << 3) + p] = vrr[it][j];
            }
        }
    };

    bf16x8 vr[2];
    stageK(0, 0);
    loadV(0, vr);
    writeV(vr);
    float m_run = -3e38f;
    float l_run = 0.f;
    floatx4 ctx[4] = {};
    __syncthreads();

    for (int kt = 0; kt < 16; kt++) {
        const int buf = kt & 1;
        const int kp0 = kt * 64;
        if (kt < 15) {
            stageK(kt + 1, buf ^ 1);
            loadV(kt + 1, vr);
        }
        const int ksl0 = (quad ^ (l16 & 7)) * 8;
        const int ksl1 = ((quad + 4) ^ (l16 & 7)) * 8;
        floatx4 s[4];
#pragma unroll
        for (int nj = 0; nj < 4; nj++) {
            const __bf16* kr = &Ks[buf][(nj * 16 + l16) * 64];
            bf16x8 k0 = *(const bf16x8*)&kr[ksl0];
            bf16x8 k1 = *(const bf16x8*)&kr[ksl1];
            floatx4 z = {0.f, 0.f, 0.f, 0.f};
            s[nj] = __builtin_amdgcn_mfma_f32_16x16x32_bf16(k0, aq0, z, 0, 0, 0);
            s[nj] = __builtin_amdgcn_mfma_f32_16x16x32_bf16(k1, aq1, s[nj], 0, 0, 0);
        }
#pragma unroll
        for (int nj = 0; nj < 4; nj++) {
            floatx4 m4 = *(const floatx4*)&mask_f[kp0 + nj * 16 + quad * 4];
#pragma unroll
            for (int r = 0; r < 4; r++) s[nj][r] += m4[r];
        }
        float mx = -3e38f;
#pragma unroll
        for (int nj = 0; nj < 4; nj++)
#pragma unroll
            for (int r = 0; r < 4; r++) mx = fmaxf(mx, s[nj][r]);
        mx = fmaxf(mx, __shfl_xor(mx, 16, 64));
        mx = fmaxf(mx, __shfl_xor(mx, 32, 64));
        const float mn = fmaxf(m_run, mx);
        const float alpha = __expf(m_run - mn);
        m_run = mn;
        float rs = 0.f;
#pragma unroll
        for (int nj = 0; nj < 4; nj++)
#pragma unroll
            for (int r = 0; r < 4; r++) {
                float p = __expf(s[nj][r] - mn);
                s[nj][r] = p;
                rs += p;
            }
        rs += __shfl_xor(rs, 16, 64);
        rs += __shfl_xor(rs, 32, 64);
        l_run = l_run * alpha + rs;
        float al[4];
#pragma unroll
        for (int r = 0; r < 4; r++) al[r] = __shfl(alpha, quad * 4 + r, 64);
        {
            char* rowp = (char*)&Ps2[w][l16][0];
#pragma unroll
            for (int nj = 0; nj < 4; nj++) {
                union { uint2 u2; unsigned short us[4]; } pk;
#pragma unroll
                for (int r = 0; r < 4; r++) {
                    __bf16 bv = (__bf16)s[nj][r];
                    pk.us[r] = *(unsigned short*)&bv;
                }
                *(uint2*)(rowp + ((nj * 32 + quad * 8) ^ key)) = pk.u2;
            }
        }
        bf16x8 pa0 = *(const bf16x8*)((char*)&Ps2[w][l16][0] + ((quad * 16) ^ key));
        bf16x8 pa1 = *(const bf16x8*)((char*)&Ps2[w][l16][0] + ((64 + quad * 16) ^ key));
#pragma unroll
        for (int dj = 0; dj < 4; dj++) {
#pragma unroll
            for (int r = 0; r < 4; r++) ctx[dj][r] *= al[r];
            const int chl = dj * 16 + l16;
            const int Xc = ((chl >> 3) ^ (chl & 7)) & 7;
            bf16x8 bv0 = *(const bf16x8*)&Vs[chl * 64 + (((quad ^ Xc) & 7) << 3)];
            bf16x8 bv1 = *(const bf16x8*)&Vs[chl * 64 + ((((quad + 4) ^ Xc) & 7) << 3)];
            ctx[dj] = __builtin_amdgcn_mfma_f32_16x16x32_bf16(pa0, bv0, ctx[dj], 0, 0, 0);
            ctx[dj] = __builtin_amdgcn_mfma_f32_16x16x32_bf16(pa1, bv1, ctx[dj], 0, 0, 0);
        }
        __syncthreads();
        if (kt < 15) writeV(vr);
        __syncthreads();
    }
    float ll[4];
#pragma unroll
    for (int r = 0; r < 4; r++) ll[r] = __shfl(l_run, quad * 4 + r, 64);
#pragma unroll
    for (int dj = 0; dj < 4; dj++)
#pragma unroll
        for (int r = 0; r < 4; r++) {
            int q = w * 16 + quad * 4 + r;
            O[((size_t)(b * 64 + q)) * 256 + h * HD + dj * 16 + l16] = (__bf16)(ctx[dj][r] / ll[r]);
        }
}

// ---------------- LayerNorm(residual) ----------------
__device__ __forceinline__ float blockSum256(float v, float* red)
{
#pragma unroll
    for (int off = 32; off >= 1; off >>= 1) v += __shfl_down(v, off, 64);
    int wave = threadIdx.x >> 6, lane = threadIdx.x & 63;
    if (lane == 0) red[wave] = v;
    __syncthreads();
    float s = red[0] + red[1] + red[2] + red[3];
    __syncthreads();
    return s;
}

__global__ __launch_bounds__(256) void lnres_k(const float* __restrict__ A,
    const float* __restrict__ Bb, const float* __restrict__ g,
    const float* __restrict__ be, float* __restrict__ Y, __bf16* __restrict__ Yb)
{
    __shared__ float red[4];
    int r = blockIdx.x, t = threadIdx.x;
    float v = A[(size_t)r * 256 + t] + Bb[(size_t)r * 256 + t];
    float mean = blockSum256(v, red) * (1.f / 256.f);
    float d = v - mean;
    float var = blockSum256(d * d, red) * (1.f / 256.f);
    float o = d * rsqrtf(var + 1e-5f) * g[t] + be[t];
    Y[(size_t)r * 256 + t] = o;
    if (Yb) Yb[(size_t)r * 256 + t] = (__bf16)o;
}

// ---------------- fused tail: LN2(residual) + mean-pool + fc1 + fc2 ----------
__global__ __launch_bounds__(256) void head2_k(const float* __restrict__ A,
    const float* __restrict__ Bb, const float* __restrict__ g,
    const float* __restrict__ be,
    const float* __restrict__ fc1w, const float* __restrict__ fc1b,
    const float* __restrict__ fc2w, const float* __restrict__ fc2b,
    float* __restrict__ out)
{
    __shared__ float pooled4[4][256];
    __shared__ float pooled[256];
    __shared__ float h[256];
    __shared__ float red[4];
    const int b = blockIdx.x, t = threadIdx.x;
    const int wv = t >> 6, lane = t & 63;
    const int ch = lane * 4;
    float g0 = g[ch], g1 = g[ch + 1], g2 = g[ch + 2], g3 = g[ch + 3];
    float b0 = be[ch], b1v = be[ch + 1], b2v = be[ch + 2], b3v = be[ch + 3];
    float accp0 = 0.f, accp1 = 0.f, accp2 = 0.f, accp3 = 0.f;
    for (int r = wv; r < 64; r += 4) {
        const size_t base = (size_t)(b * 64 + r) * 256 + ch;
        float v0 = A[base + 0] + Bb[base + 0];
        float v1 = A[base + 1] + Bb[base + 1];
        float v2 = A[base + 2] + Bb[base + 2];
        float v3 = A[base + 3] + Bb[base + 3];
        float s = v0 + v1 + v2 + v3;
#pragma unroll
        for (int off = 32; off >= 1; off >>= 1) s += __shfl_xor(s, off, 64);
        float mean = s * (1.f / 256.f);
        float c0 = v0 - mean, c1 = v1 - mean, c2 = v2 - mean, c3 = v3 - mean;
        float s2 = c0 * c0 + c1 * c1 + c2 * c2 + c3 * c3;
#pragma unroll
        for (int off = 32; off >= 1; off >>= 1) s2 += __shfl_xor(s2, off, 64);
        float rstd = rsqrtf(s2 * (1.f / 256.f) + 1e-5f);
        accp0 += c0 * rstd * g0 + b0;
        accp1 += c1 * rstd * g1 + b1v;
        accp2 += c2 * rstd * g2 + b2v;
        accp3 += c3 * rstd * g3 + b3v;
    }
    pooled4[wv][ch + 0] = accp0;
    pooled4[wv][ch + 1] = accp1;
    pooled4[wv][ch + 2] = accp2;
    pooled4[wv][ch + 3] = accp3;
    __syncthreads();
    pooled[t] = (pooled4[0][t] + pooled4[1][t] + pooled4[2][t] + pooled4[3][t])
                / (64.f + 1e-6f);
    __syncthreads();
    float a = 0.f;
    for (int k = 0; k < 256; k += 4) {
        a += pooled[k + 0] * fc1w[(k + 0) * 256 + t];
        a += pooled[k + 1] * fc1w[(k + 1) * 256 + t];
        a += pooled[k + 2] * fc1w[(k + 2) * 256 + t];
        a += pooled[k + 3] * fc1w[(k + 3) * 256 + t];
    }
    h[t] = fmaxf(a + fc1b[t], 0.f);
    __syncthreads();
    float p = h[t] * fc2w[t];
    p = blockSum256(p, red);
    if (t == 0) out[b] = p + fc2b[0];
}

// ---------------- launch ----------------
extern "C" void kernel_launch(void* const* d_in, const int* in_sizes, int n_in,
                              void* d_out, int out_size, void* d_ws, size_t ws_size,
                              hipStream_t stream)
{
    const float* x     = (const float*)d_in[0];
    const int*   ei    = (const int*)d_in[1];
    const int*   pseq  = (const int*)d_in[3];
    const float* w1  = (const float*)d_in[4];
    const float* as1 = (const float*)d_in[5];
    const float* ad1 = (const float*)d_in[6];
    const float* b1  = (const float*)d_in[7];
    const float* w2  = (const float*)d_in[8];
    const float* as2 = (const float*)d_in[9];
    const float* ad2 = (const float*)d_in[10];
    const float* b2  = (const float*)d_in[11];
    const float* w3  = (const float*)d_in[12];
    const float* as3 = (const float*)d_in[13];
    const float* ad3 = (const float*)d_in[14];
    const float* b3  = (const float*)d_in[15];
    const float* emb    = (const float*)d_in[16];
    const float* conv_w = (const float*)d_in[17];
    const float* conv_b = (const float*)d_in[18];
    const float* wq = (const float*)d_in[19];
    const float* bq = (const float*)d_in[20];
    const float* wk = (const float*)d_in[21];
    const float* bk = (const float*)d_in[22];
    const float* wv = (const float*)d_in[23];
    const float* bv = (const float*)d_in[24];
    const float* wo = (const float*)d_in[25];
    const float* bo = (const float*)d_in[26];
    const float* ln1_g = (const float*)d_in[27];
    const float* ln1_b = (const float*)d_in[28];
    const float* ffw1  = (const float*)d_in[29];
    const float* ffb1  = (const float*)d_in[30];
    const float* ffw2  = (const float*)d_in[31];
    const float* ffb2  = (const float*)d_in[32];
    const float* ln2_g = (const float*)d_in[33];
    const float* ln2_b = (const float*)d_in[34];
    const float* fc1_w = (const float*)d_in[35];
    const float* fc1_b = (const float*)d_in[36];
    const float* fc2_w = (const float*)d_in[37];
    const float* fc2_b = (const float*)d_in[38];
    (void)in_sizes; (void)n_in; (void)out_size;

    char* ws = (char*)d_ws;
    size_t off = 0;
    auto alloc = [&](size_t bytes) -> char* {
        char* p = ws + off;
        off += (bytes + 255) & ~(size_t)255;
        return p;
    };
    // ---- fixed arena ----
    __bf16* hgb  = (__bf16*)alloc((size_t)NAT * 512 * 2);
    float* og    = (float*)alloc((size_t)NAT * 512 * 4);
    float* hb0   = (float*)alloc((size_t)NAT * 256 * 4);
    float* hb1   = (float*)alloc((size_t)NAT * 256 * 4);
    __bf16* xb   = (__bf16*)alloc((size_t)NAT * FIN * 2);
    __bf16* hbb  = (__bf16*)alloc((size_t)NAT * 256 * 2);
    __bf16* qbb  = (__bf16*)alloc((size_t)NAT * 256 * 2);
    __bf16* ctxbb= (__bf16*)alloc((size_t)NAT * 256 * 2);
    __bf16* ybb  = (__bf16*)alloc((size_t)NAT * 256 * 2);
    float* a_s   = (float*)alloc((size_t)NAT * 2 * 4);
    float* a_d   = (float*)alloc((size_t)NAT * 2 * 4);
    float* asd_p = (float*)alloc((size_t)16 * NAT * 4);
    int* deg     = (int*)alloc((size_t)NAT * 4);
    int* fill    = (int*)alloc((size_t)NAT * 4);
    int* rowptr  = (int*)alloc((size_t)(NAT + 1) * 4);
    int* csrc    = (int*)alloc((size_t)NED * 4);
    int* cdst    = (int*)alloc((size_t)NED * 4);
    float* tap   = (float*)alloc((size_t)3 * 22 * 256 * 4);
    __bf16* ptab = (__bf16*)alloc((size_t)NTAB * 256 * 2);
    __bf16* Ktab = (__bf16*)alloc((size_t)NTAB * 256 * 2);   // [4][NTAB][64]
    __bf16* Vtab = (__bf16*)alloc((size_t)NTAB * 256 * 2);   // [4][NTAB][64]
    unsigned short* tid16 = (unsigned short*)alloc((size_t)BGR * LPN * 2);
    __bf16* w1T  = (__bf16*)alloc((size_t)512 * 64 * 2);
    __bf16* w2T  = (__bf16*)alloc((size_t)512 * 256 * 2);
    __bf16* w3T  = (__bf16*)alloc((size_t)512 * 256 * 2);
    __bf16* wkT  = (__bf16*)alloc((size_t)256 * 256 * 2);
    __bf16* wvT  = (__bf16*)alloc((size_t)256 * 256 * 2);
    __bf16* wqT  = (__bf16*)alloc((size_t)256 * 256 * 2);
    __bf16* woT  = (__bf16*)alloc((size_t)256 * 256 * 2);
    __bf16* f1T  = (__bf16*)alloc((size_t)1024 * 256 * 2);
    __bf16* f2T  = (__bf16*)alloc((size_t)256 * 1024 * 2);
    // ---- variable region (FF intermediates) ----
    size_t fixed_end = off;
    char* region   = ws + fixed_end;
    __bf16* ffbb   = (__bf16*)region;
    float* attno = og;
    float* ybuf  = og + (size_t)NAT * 256;
    float* ff2o  = hb1;
    (void)ws_size;

    // ---------------- zero deg/fill + tap ----------------
    hipMemsetAsync(deg, 0, (size_t)NAT * 8, stream);   // deg + fill (adjacent)
    hipMemsetAsync(tap, 0, (size_t)3 * 22 * 256 * 4, stream);

    // ---------------- fused preamble 1: deg + tap + tid + cvtall --------------
    {
        Segs S;
        const float* srcs[10] = {x, w1, w2, w3, wk, wv, wq, wo, ffw1, ffw2};
        __bf16* dsts[10] = {xb, w1T, w2T, w3T, wkT, wvT, wqT, woT, f1T, f2T};
        int kd[10] = {0, 64, 256, 256, 256, 256, 256, 256, 256, 1024};
        int nd[10] = {0, 512, 512, 512, 256, 256, 256, 256, 1024, 256};
        int md[10] = {0, 1, 1, 1, 1, 1, 1, 1, 1, 1};
        int cnt[10] = {NAT * FIN, 32768, 131072, 131072,
                       65536, 65536, 65536, 65536, 262144, 262144};
        int run = 0;
        for (int i = 0; i < 10; i++) {
            S.src[i] = srcs[i]; S.dst[i] = dsts[i];
            S.kdim[i] = kd[i]; S.ndim[i] = nd[i]; S.mode[i] = md[i];
            S.start[i] = run; run += cnt[i];
        }
        S.start[10] = run; S.start[11] = run; S.start[12] = run;
        int grid1 = 1544 + (run + 255) / 256;
        misc1_k<<<grid1, 256, 0, stream>>>(ei, deg, emb, conv_w, tap, pseq, tid16, S, run);
    }

    // ---------------- fused preamble 2: scan + ptab ----------------
    misc2_k<<<1 + NTAB / 8, 256, 0, stream>>>(deg, rowptr, tap, conv_b, ptab);

    // ---------------- fused preamble 3: scat + kvtab ----------------
    misc3_k<<<128 + 4 * (NTAB / 128), 512, 0, stream>>>(ei, fill, rowptr, csrc, cdst,
                                                        ptab, wkT, wvT, bk, bv, Ktab, Vtab);

    // ---------------- ligand GNN: 3 GAT layers ----------------
    const __bf16* WT[3] = {w1T, w2T, w3T};
    const float* asl[3] = {as1, as2, as3};
    const float* adl[3] = {ad1, ad2, ad3};
    const float* bl[3]  = {b1, b2, b3};
    float* houts[3] = {nullptr, nullptr, hb0};
    const __bf16* hinb = xb;
    int Kdim = FIN;
    for (int l = 0; l < 3; l++) {
        gemm_gat<<<dim3(4, NAT / 128), 512, 0, stream>>>(hinb, WT[l], asl[l], adl[l], hgb, asd_p, Kdim);
        fold_k<<<NAT / 256, 256, 0, stream>>>(asd_p, a_s, a_d);
        gat_agg<<<NAT / 4, 256, 0, stream>>>(rowptr, csrc, hgb, a_s, a_d, bl[l], houts[l], hbb);
        hinb = hbb;
        Kdim = HID;
    }
    const float* lig = hb0;
    const __bf16* ligb = hbb;

    // ---------------- Q projection (scale 1/8 folded in), 64-col tiles -------
    gemm_mfma<0, 1, 0, 0, 64><<<dim3(4, NAT / 128), 512, 0, stream>>>(ligb, wqT, bq, qbb, NAT, 256, 256, 0.125f);

    // ---------------- cross-attention: single dispatch ----------------
    attn6_k<<<BGR * 4, 256, 0, stream>>>(qbb, Ktab, Vtab, tid16, ctxbb);

    // ---------------- attention out proj + LN + FFN + fused tail -------------
    gemm_mfma<0, 0, 0, 0, 64><<<dim3(4, NAT / 128), 512, 0, stream>>>(ctxbb, woT, bo, attno, NAT, 256, 256, 1.f);
    lnres_k<<<NAT, 256, 0, stream>>>(lig, attno, ln1_g, ln1_b, ybuf, ybb);
    gemm_mfma<2, 1, 0, 0, 128><<<dim3(8, NAT / 128), 512, 0, stream>>>(ybb, f1T, ffb1, ffbb, NAT, 1024, 256, 1.f);
    gemm_mfma<0, 0, 0, 0, 64><<<dim3(4, NAT / 128), 512, 0, stream>>>(ffbb, f2T, ffb2, ff2o, NAT, 256, 1024, 1.f);
    head2_k<<<BGR, 256, 0, stream>>>(ybuf, ff2o, ln2_g, ln2_b,
                                     fc1_w, fc1_b, fc2_w, fc2_b, (float*)d_out);
}